// Round 7
// baseline (486.971 us; speedup 1.0000x reference)
//
#include <hip/hip_runtime.h>
#include <hip/hip_bf16.h>
#include <math.h>

#define N_NODES 50000
#define N_EDGES 800000
#define NCLASS 40
#define MAXE 64

using f32x4 = __attribute__((ext_vector_type(4))) float;
using s16x8 = __attribute__((ext_vector_type(8))) short;

// ---------------- edge dtype detect ----------------
__global__ void detect_i64(const int* __restrict__ raw, int* __restrict__ flag) {
  int t = threadIdx.x;
  int v = raw[2 * t + 1];
  unsigned long long any = __ballot(v != 0);
  if (t == 0) flag[0] = (any == 0ULL) ? 1 : 0;
}

// ---------------- CSR build (read raw directly, no staging) ----------------
__global__ void count_raw(const int* __restrict__ raw, const int* __restrict__ flag,
                          int* __restrict__ deg) {
  int e = blockIdx.x * blockDim.x + threadIdx.x;
  if (e >= N_EDGES) return;
  int d = flag[0] ? raw[2 * N_EDGES + 2 * e] : raw[N_EDGES + e];
  atomicAdd(&deg[d], 1);
}

__global__ void scan_bsum(const int* __restrict__ deg, int* __restrict__ bsums) {
  __shared__ int sm[256];
  int t = threadIdx.x;
  int i = blockIdx.x * 256 + t;
  sm[t] = (i < N_NODES) ? deg[i] : 0;
  __syncthreads();
  for (int off = 128; off > 0; off >>= 1) {
    if (t < off) sm[t] += sm[t + off];
    __syncthreads();
  }
  if (t == 0) bsums[blockIdx.x] = sm[0];
}

__global__ void scan_offsets(int* __restrict__ bsums, int* __restrict__ rowp, int nb) {
  __shared__ int sm[256];
  int t = threadIdx.x;
  int v = (t < nb) ? bsums[t] : 0;
  sm[t] = v;
  __syncthreads();
  for (int off = 1; off < 256; off <<= 1) {
    int add = (t >= off) ? sm[t - off] : 0;
    __syncthreads();
    sm[t] += add;
    __syncthreads();
  }
  if (t < nb) bsums[t] = sm[t] - v;
  if (t == 0) rowp[N_NODES] = N_EDGES;
}

__global__ void scan_final(const int* __restrict__ deg, const int* __restrict__ bsums,
                           int* __restrict__ rowp, int* __restrict__ cursor) {
  __shared__ int sm[256];
  int t = threadIdx.x;
  int i = blockIdx.x * 256 + t;
  int v = (i < N_NODES) ? deg[i] : 0;
  sm[t] = v;
  __syncthreads();
  for (int off = 1; off < 256; off <<= 1) {
    int add = (t >= off) ? sm[t - off] : 0;
    __syncthreads();
    sm[t] += add;
    __syncthreads();
  }
  int excl = sm[t] - v + bsums[blockIdx.x];
  if (i < N_NODES) { rowp[i] = excl; cursor[i] = excl; }
}

__global__ void scatter_raw(const int* __restrict__ raw, const int* __restrict__ flag,
                            int* __restrict__ cursor, int* __restrict__ srcs) {
  int e = blockIdx.x * blockDim.x + threadIdx.x;
  if (e >= N_EDGES) return;
  int f = flag[0];
  int s = f ? raw[2 * e] : raw[e];
  int d = f ? raw[2 * N_EDGES + 2 * e] : raw[N_EDGES + e];
  int pos = atomicAdd(&cursor[d], 1);
  srcs[pos] = s;
}

// ---------------- weight prep (all three layers in one launch) ----------------
__global__ void prep_w(const float* __restrict__ W1, const float* __restrict__ W2,
                       const float* __restrict__ W3,
                       __hip_bfloat16* __restrict__ WT1, __hip_bfloat16* __restrict__ WT2,
                       __hip_bfloat16* __restrict__ WT3) {
  int b = blockIdx.x, t = threadIdx.x;
  if (b < 256) {
    int id = b * 256 + t;
    int n = id >> 8, k = id & 255;
    WT1[n * 256 + k] = __float2bfloat16(W1[k * 256 + n]);
  } else if (b < 512) {
    int id = (b - 256) * 256 + t;
    int n = id >> 8, k = id & 255;
    WT2[n * 256 + k] = __float2bfloat16(W2[k * 256 + n]);
  } else {
    int id = (b - 512) * 256 + t;
    int n = id >> 8, k = id & 255;
    WT3[n * 256 + k] = (n < NCLASS) ? __float2bfloat16(W3[k * NCLASS + n]) : __float2bfloat16(0.f);
  }
}

__global__ void cast_x(const float* __restrict__ x, __hip_bfloat16* __restrict__ xb) {
  int id = blockIdx.x * 256 + threadIdx.x;
  float4 v = *reinterpret_cast<const float4*>(x + (size_t)id * 4);
  ushort4 u;
  __hip_bfloat16 b;
  b = __float2bfloat16(v.x); u.x = *(unsigned short*)&b;
  b = __float2bfloat16(v.y); u.y = *(unsigned short*)&b;
  b = __float2bfloat16(v.z); u.z = *(unsigned short*)&b;
  b = __float2bfloat16(v.w); u.w = *(unsigned short*)&b;
  *reinterpret_cast<ushort4*>((unsigned short*)xb + (size_t)id * 4) = u;
}

// ---------------- bf16 MFMA GEMM, layers 1-2, fused el/er + bf16-out epilogue ----------
__global__ __launch_bounds__(256) void gemm_gat12(const __hip_bfloat16* __restrict__ A,
                                                  const __hip_bfloat16* __restrict__ WT,
                                                  const float* __restrict__ al,
                                                  const float* __restrict__ ar,
                                                  __hip_bfloat16* __restrict__ hb,
                                                  float* __restrict__ el,
                                                  float* __restrict__ er) {
  constexpr int MREP = 4, NREP = 4;
  __shared__ __align__(16) __hip_bfloat16 As[128][40];
  __shared__ __align__(16) __hip_bfloat16 Bs[128][40];

  int t = threadIdx.x;
  int lane = t & 63, wave = t >> 6;
  int wr = wave >> 1, wc = wave & 1;
  int row0 = blockIdx.x * 128, col0 = blockIdx.y * 128;
  int ln = lane & 15;
  int kc8 = (lane >> 4) * 8;

  f32x4 acc[MREP][NREP];
  const f32x4 fz = {0.f, 0.f, 0.f, 0.f};
#pragma unroll
  for (int m = 0; m < MREP; ++m)
#pragma unroll
    for (int n = 0; n < NREP; ++n) acc[m][n] = fz;

  for (int k0 = 0; k0 < 256; k0 += 32) {
#pragma unroll
    for (int it = 0; it < 2; ++it) {
      int c = t + it * 256;
      int r = c >> 2, kc = (c & 3) * 8;
      int grow = row0 + r;
      f32x4 v = fz;
      if (grow < N_NODES)
        v = *reinterpret_cast<const f32x4*>(A + (size_t)grow * 256 + k0 + kc);
      *reinterpret_cast<f32x4*>(&As[r][kc]) = v;
    }
#pragma unroll
    for (int it = 0; it < 2; ++it) {
      int c = t + it * 256;
      int r = c >> 2, kc = (c & 3) * 8;
      f32x4 v = *reinterpret_cast<const f32x4*>(WT + (size_t)(col0 + r) * 256 + k0 + kc);
      *reinterpret_cast<f32x4*>(&Bs[r][kc]) = v;
    }
    __syncthreads();
    s16x8 af[MREP], bfr[NREP];
#pragma unroll
    for (int m = 0; m < MREP; ++m)
      af[m] = *reinterpret_cast<const s16x8*>(&As[wr * 64 + m * 16 + ln][kc8]);
#pragma unroll
    for (int n = 0; n < NREP; ++n)
      bfr[n] = *reinterpret_cast<const s16x8*>(&Bs[wc * 64 + n * 16 + ln][kc8]);
#pragma unroll
    for (int m = 0; m < MREP; ++m)
#pragma unroll
      for (int n = 0; n < NREP; ++n)
        acc[m][n] = __builtin_amdgcn_mfma_f32_16x16x32_bf16(af[m], bfr[n], acc[m][n], 0, 0, 0);
    __syncthreads();
  }

  int head = blockIdx.y * 2 + wc;
  float alv[NREP], arv[NREP];
#pragma unroll
  for (int n = 0; n < NREP; ++n) {
    int c = head * 64 + n * 16 + ln;
    alv[n] = al[c];
    arv[n] = ar[c];
  }
#pragma unroll
  for (int m = 0; m < MREP; ++m) {
#pragma unroll
    for (int r = 0; r < 4; ++r) {
      int row = row0 + wr * 64 + m * 16 + (lane >> 4) * 4 + r;
      bool ok = row < N_NODES;
      float pl = 0.f, pr = 0.f;
#pragma unroll
      for (int n = 0; n < NREP; ++n) {
        float v = acc[m][n][r];
        pl += v * alv[n];
        pr += v * arv[n];
        if (ok) hb[(size_t)row * 256 + head * 64 + n * 16 + ln] = __float2bfloat16(v);
      }
      for (int off = 1; off < 16; off <<= 1) {
        pl += __shfl_xor(pl, off);
        pr += __shfl_xor(pr, off);
      }
      if (ln == 0 && ok) {
        el[row * 4 + head] = pl;
        er[row * 4 + head] = pr;
      }
    }
  }
}

// ---------------- layer-3 GEMM: fused el/er, bf16 h3 out ----------------
__global__ __launch_bounds__(256) void gemm_gat3(const __hip_bfloat16* __restrict__ A,
                                                 const __hip_bfloat16* __restrict__ WT,
                                                 const float* __restrict__ al,
                                                 const float* __restrict__ ar,
                                                 __hip_bfloat16* __restrict__ h3b,
                                                 float* __restrict__ el3,
                                                 float* __restrict__ er3) {
  constexpr int MREP = 2, NREP = 4;
  __shared__ __align__(16) __hip_bfloat16 As[128][40];
  __shared__ __align__(16) __hip_bfloat16 Bs[64][40];

  int t = threadIdx.x;
  int lane = t & 63, wave = t >> 6;
  int row0 = blockIdx.x * 128;
  int ln = lane & 15;
  int kc8 = (lane >> 4) * 8;

  f32x4 acc[MREP][NREP];
  const f32x4 fz = {0.f, 0.f, 0.f, 0.f};
#pragma unroll
  for (int m = 0; m < MREP; ++m)
#pragma unroll
    for (int n = 0; n < NREP; ++n) acc[m][n] = fz;

  for (int k0 = 0; k0 < 256; k0 += 32) {
#pragma unroll
    for (int it = 0; it < 2; ++it) {
      int c = t + it * 256;
      int r = c >> 2, kc = (c & 3) * 8;
      int grow = row0 + r;
      f32x4 v = fz;
      if (grow < N_NODES)
        v = *reinterpret_cast<const f32x4*>(A + (size_t)grow * 256 + k0 + kc);
      *reinterpret_cast<f32x4*>(&As[r][kc]) = v;
    }
    {
      int c = t;
      int r = c >> 2, kc = (c & 3) * 8;
      f32x4 v = *reinterpret_cast<const f32x4*>(WT + (size_t)r * 256 + k0 + kc);
      *reinterpret_cast<f32x4*>(&Bs[r][kc]) = v;
    }
    __syncthreads();
    s16x8 af[MREP], bfr[NREP];
#pragma unroll
    for (int m = 0; m < MREP; ++m)
      af[m] = *reinterpret_cast<const s16x8*>(&As[wave * 32 + m * 16 + ln][kc8]);
#pragma unroll
    for (int n = 0; n < NREP; ++n)
      bfr[n] = *reinterpret_cast<const s16x8*>(&Bs[n * 16 + ln][kc8]);
#pragma unroll
    for (int m = 0; m < MREP; ++m)
#pragma unroll
      for (int n = 0; n < NREP; ++n)
        acc[m][n] = __builtin_amdgcn_mfma_f32_16x16x32_bf16(af[m], bfr[n], acc[m][n], 0, 0, 0);
    __syncthreads();
  }

  float alv[NREP], arv[NREP];
#pragma unroll
  for (int n = 0; n < NREP; ++n) {
    int c = n * 16 + ln;
    alv[n] = (c < NCLASS) ? al[c] : 0.f;
    arv[n] = (c < NCLASS) ? ar[c] : 0.f;
  }
#pragma unroll
  for (int m = 0; m < MREP; ++m) {
#pragma unroll
    for (int r = 0; r < 4; ++r) {
      int row = row0 + wave * 32 + m * 16 + (lane >> 4) * 4 + r;
      bool ok = row < N_NODES;
      float pl = 0.f, pr = 0.f;
#pragma unroll
      for (int n = 0; n < NREP; ++n) {
        float v = acc[m][n][r];
        pl += v * alv[n];
        pr += v * arv[n];
        if (ok) h3b[(size_t)row * 64 + n * 16 + ln] = __float2bfloat16(v);
      }
      for (int off = 1; off < 16; off <<= 1) {
        pl += __shfl_xor(pl, off);
        pr += __shfl_xor(pr, off);
      }
      if (ln == 0 && ok) {
        el3[row] = pl;
        er3[row] = pr;
      }
    }
  }
}

// ---------------- fused stats + gather, layers 1-2: 2 waves/block, 1 node/wave -------
// Pass A: lane owns edge j (float4 el load = all 4 heads), 4 per-head online (m,l),
// 64-lane butterfly per head. Scores cached in LDS [MAXE][4]. Pass B: lane handles
// dims 4*lane..4*lane+3 via one dwordx2 per edge, 4-edge unroll.
__global__ __launch_bounds__(128) void agg_fused(const __hip_bfloat16* __restrict__ hb,
                                                 const float* __restrict__ el,
                                                 const float* __restrict__ er,
                                                 const float* __restrict__ bias,
                                                 const int* __restrict__ rowp,
                                                 const int* __restrict__ srcs,
                                                 __hip_bfloat16* __restrict__ ob) {
  __shared__ float eld[2][MAXE * 4];
  int wv = threadIdx.x >> 6, lane = threadIdx.x & 63;
  int n = blockIdx.x * 2 + wv;
  float* ew = eld[wv];
  int i0 = rowp[n], deg = rowp[n + 1] - i0;
  float4 ern4 = *reinterpret_cast<const float4*>(er + (size_t)n * 4);
  float m0 = -1e30f, m1 = -1e30f, m2 = -1e30f, m3 = -1e30f;
  float l0 = 0.f, l1 = 0.f, l2 = 0.f, l3 = 0.f;
  for (int j = lane; j < deg; j += 64) {
    int s = srcs[i0 + j];
    float4 e4 = *reinterpret_cast<const float4*>(el + (size_t)s * 4);
    float e0 = e4.x + ern4.x; e0 = (e0 >= 0.f) ? e0 : 0.2f * e0;
    float e1 = e4.y + ern4.y; e1 = (e1 >= 0.f) ? e1 : 0.2f * e1;
    float e2 = e4.z + ern4.z; e2 = (e2 >= 0.f) ? e2 : 0.2f * e2;
    float e3 = e4.w + ern4.w; e3 = (e3 >= 0.f) ? e3 : 0.2f * e3;
    if (j < MAXE)
      *reinterpret_cast<float4*>(&ew[j * 4]) = make_float4(e0, e1, e2, e3);
    float nm;
    nm = fmaxf(m0, e0); l0 = l0 * __expf(m0 - nm) + __expf(e0 - nm); m0 = nm;
    nm = fmaxf(m1, e1); l1 = l1 * __expf(m1 - nm) + __expf(e1 - nm); m1 = nm;
    nm = fmaxf(m2, e2); l2 = l2 * __expf(m2 - nm) + __expf(e2 - nm); m2 = nm;
    nm = fmaxf(m3, e3); l3 = l3 * __expf(m3 - nm) + __expf(e3 - nm); m3 = nm;
  }
#pragma unroll
  for (int off = 1; off < 64; off <<= 1) {
    float mo, lo, nm;
    mo = __shfl_xor(m0, off); lo = __shfl_xor(l0, off);
    nm = fmaxf(m0, mo); l0 = l0 * __expf(m0 - nm) + lo * __expf(mo - nm); m0 = nm;
    mo = __shfl_xor(m1, off); lo = __shfl_xor(l1, off);
    nm = fmaxf(m1, mo); l1 = l1 * __expf(m1 - nm) + lo * __expf(mo - nm); m1 = nm;
    mo = __shfl_xor(m2, off); lo = __shfl_xor(l2, off);
    nm = fmaxf(m2, mo); l2 = l2 * __expf(m2 - nm) + lo * __expf(mo - nm); m2 = nm;
    mo = __shfl_xor(m3, off); lo = __shfl_xor(l3, off);
    nm = fmaxf(m3, mo); l3 = l3 * __expf(m3 - nm) + lo * __expf(mo - nm); m3 = nm;
  }
  float inv0 = (l0 > 0.f) ? (1.f / l0) : 0.f;
  float inv1 = (l1 > 0.f) ? (1.f / l1) : 0.f;
  float inv2 = (l2 > 0.f) ? (1.f / l2) : 0.f;
  float inv3 = (l3 > 0.f) ? (1.f / l3) : 0.f;
  __syncthreads();
  int ecount = ((deg < MAXE) ? deg : MAXE) * 4;
  {
    int hh = lane & 3;
    float mm = (hh == 0) ? m0 : (hh == 1) ? m1 : (hh == 2) ? m2 : m3;
    float iv = (hh == 0) ? inv0 : (hh == 1) ? inv1 : (hh == 2) ? inv2 : inv3;
    for (int k = lane; k < ecount; k += 64) ew[k] = __expf(ew[k] - mm) * iv;
  }
  __syncthreads();
  // pass B
  int head = lane >> 4;
  float mh = (head == 0) ? m0 : (head == 1) ? m1 : (head == 2) ? m2 : m3;
  float ivh = (head == 0) ? inv0 : (head == 1) ? inv1 : (head == 2) ? inv2 : inv3;
  float ernh = (head == 0) ? ern4.x : (head == 1) ? ern4.y : (head == 2) ? ern4.z : ern4.w;
  const uint2* hp = (const uint2*)hb;
  float4 A = make_float4(0.f, 0.f, 0.f, 0.f);
  float4 B = make_float4(0.f, 0.f, 0.f, 0.f);
  float4 C = make_float4(0.f, 0.f, 0.f, 0.f);
  float4 D = make_float4(0.f, 0.f, 0.f, 0.f);
  int j = 0;
  for (; j + 3 < deg; j += 4) {
    int s0 = srcs[i0 + j], s1 = srcs[i0 + j + 1], s2 = srcs[i0 + j + 2], s3 = srcs[i0 + j + 3];
    float w0, w1, w2, w3;
    if (j + 3 < MAXE) {
      w0 = ew[(j + 0) * 4 + head];
      w1 = ew[(j + 1) * 4 + head];
      w2 = ew[(j + 2) * 4 + head];
      w3 = ew[(j + 3) * 4 + head];
    } else {
      float e0 = el[s0 * 4 + head] + ernh; e0 = (e0 >= 0.f) ? e0 : 0.2f * e0;
      float e1 = el[s1 * 4 + head] + ernh; e1 = (e1 >= 0.f) ? e1 : 0.2f * e1;
      float e2 = el[s2 * 4 + head] + ernh; e2 = (e2 >= 0.f) ? e2 : 0.2f * e2;
      float e3 = el[s3 * 4 + head] + ernh; e3 = (e3 >= 0.f) ? e3 : 0.2f * e3;
      w0 = __expf(e0 - mh) * ivh;
      w1 = __expf(e1 - mh) * ivh;
      w2 = __expf(e2 - mh) * ivh;
      w3 = __expf(e3 - mh) * ivh;
    }
    uint2 h0 = hp[(size_t)s0 * 64 + lane];
    uint2 h1 = hp[(size_t)s1 * 64 + lane];
    uint2 h2 = hp[(size_t)s2 * 64 + lane];
    uint2 h3v = hp[(size_t)s3 * 64 + lane];
    A.x += w0 * __uint_as_float(h0.x << 16);
    A.y += w0 * __uint_as_float(h0.x & 0xffff0000u);
    A.z += w0 * __uint_as_float(h0.y << 16);
    A.w += w0 * __uint_as_float(h0.y & 0xffff0000u);
    B.x += w1 * __uint_as_float(h1.x << 16);
    B.y += w1 * __uint_as_float(h1.x & 0xffff0000u);
    B.z += w1 * __uint_as_float(h1.y << 16);
    B.w += w1 * __uint_as_float(h1.y & 0xffff0000u);
    C.x += w2 * __uint_as_float(h2.x << 16);
    C.y += w2 * __uint_as_float(h2.x & 0xffff0000u);
    C.z += w2 * __uint_as_float(h2.y << 16);
    C.w += w2 * __uint_as_float(h2.y & 0xffff0000u);
    D.x += w3 * __uint_as_float(h3v.x << 16);
    D.y += w3 * __uint_as_float(h3v.x & 0xffff0000u);
    D.z += w3 * __uint_as_float(h3v.y << 16);
    D.w += w3 * __uint_as_float(h3v.y & 0xffff0000u);
  }
  for (; j < deg; ++j) {
    int s0 = srcs[i0 + j];
    float w0;
    if (j < MAXE) {
      w0 = ew[j * 4 + head];
    } else {
      float e0 = el[s0 * 4 + head] + ernh; e0 = (e0 >= 0.f) ? e0 : 0.2f * e0;
      w0 = __expf(e0 - mh) * ivh;
    }
    uint2 h0 = hp[(size_t)s0 * 64 + lane];
    A.x += w0 * __uint_as_float(h0.x << 16);
    A.y += w0 * __uint_as_float(h0.x & 0xffff0000u);
    A.z += w0 * __uint_as_float(h0.y << 16);
    A.w += w0 * __uint_as_float(h0.y & 0xffff0000u);
  }
  float4 b4 = *reinterpret_cast<const float4*>(bias + (size_t)lane * 4);
  float r0 = (A.x + B.x) + (C.x + D.x) + b4.x;
  float r1 = (A.y + B.y) + (C.y + D.y) + b4.y;
  float r2 = (A.z + B.z) + (C.z + D.z) + b4.z;
  float r3 = (A.w + B.w) + (C.w + D.w) + b4.w;
  r0 = (r0 > 0.f) ? r0 : (__expf(r0) - 1.f);
  r1 = (r1 > 0.f) ? r1 : (__expf(r1) - 1.f);
  r2 = (r2 > 0.f) ? r2 : (__expf(r2) - 1.f);
  r3 = (r3 > 0.f) ? r3 : (__expf(r3) - 1.f);
  __hip_bfloat16 q0 = __float2bfloat16(r0), q1 = __float2bfloat16(r1);
  __hip_bfloat16 q2 = __float2bfloat16(r2), q3 = __float2bfloat16(r3);
  uint2 o;
  o.x = (unsigned int)(*(unsigned short*)&q0) | ((unsigned int)(*(unsigned short*)&q1) << 16);
  o.y = (unsigned int)(*(unsigned short*)&q2) | ((unsigned int)(*(unsigned short*)&q3) << 16);
  ((uint2*)ob)[(size_t)n * 64 + lane] = o;
}

// ---------------- layer 3: fused stats + gather + bias + log_softmax (2 nodes/block) --
__global__ __launch_bounds__(128) void agg_cls_fused(const __hip_bfloat16* __restrict__ h3b,
                                                     const float* __restrict__ el3,
                                                     const float* __restrict__ er3,
                                                     const float* __restrict__ bias,
                                                     const int* __restrict__ rowp,
                                                     const int* __restrict__ srcs,
                                                     float* __restrict__ out) {
  __shared__ float eldc[2][MAXE];
  int wv = threadIdx.x >> 6, lane = threadIdx.x & 63;
  int n = blockIdx.x * 2 + wv;
  float* ec = eldc[wv];
  int i0 = rowp[n], deg = rowp[n + 1] - i0;
  float ern = er3[n];
  float m = -1e30f, l = 0.f;
  for (int j = lane; j < deg; j += 64) {
    int s = srcs[i0 + j];
    float e = el3[s] + ern;
    e = (e >= 0.f) ? e : 0.2f * e;
    if (j < MAXE) ec[j] = e;
    float nm = fmaxf(m, e);
    l = l * __expf(m - nm) + __expf(e - nm);
    m = nm;
  }
#pragma unroll
  for (int off = 1; off < 64; off <<= 1) {
    float mo = __shfl_xor(m, off), lo = __shfl_xor(l, off);
    float nm = fmaxf(m, mo);
    l = l * __expf(m - nm) + lo * __expf(mo - nm);
    m = nm;
  }
  float inv = (l > 0.f) ? (1.f / l) : 0.f;
  __syncthreads();
  int ecount = (deg < MAXE) ? deg : MAXE;
  for (int k = lane; k < ecount; k += 64) ec[k] = __expf(ec[k] - m) * inv;
  __syncthreads();
  bool act2 = lane < ((NCLASS + 1) / 2);  // lane < 20, dims {2*lane, 2*lane+1}
  const unsigned int* hp3 = (const unsigned int*)h3b;
  float ax = 0.f, ay = 0.f, bx = 0.f, by = 0.f;
  int j = 0;
  for (; j + 1 < deg; j += 2) {
    int s0 = srcs[i0 + j], s1 = srcs[i0 + j + 1];
    float w0, w1;
    if (j + 1 < MAXE) {
      w0 = ec[j];
      w1 = ec[j + 1];
    } else {
      float e0 = el3[s0] + ern; e0 = (e0 >= 0.f) ? e0 : 0.2f * e0;
      float e1 = el3[s1] + ern; e1 = (e1 >= 0.f) ? e1 : 0.2f * e1;
      w0 = __expf(e0 - m) * inv;
      w1 = __expf(e1 - m) * inv;
    }
    if (act2) {
      unsigned int h0 = hp3[(size_t)s0 * 32 + lane];
      unsigned int h1 = hp3[(size_t)s1 * 32 + lane];
      ax += w0 * __uint_as_float(h0 << 16);
      ay += w0 * __uint_as_float(h0 & 0xffff0000u);
      bx += w1 * __uint_as_float(h1 << 16);
      by += w1 * __uint_as_float(h1 & 0xffff0000u);
    }
  }
  if (j < deg) {
    int s0 = srcs[i0 + j];
    float w0;
    if (j < MAXE) {
      w0 = ec[j];
    } else {
      float e0 = el3[s0] + ern; e0 = (e0 >= 0.f) ? e0 : 0.2f * e0;
      w0 = __expf(e0 - m) * inv;
    }
    if (act2) {
      unsigned int h0 = hp3[(size_t)s0 * 32 + lane];
      ax += w0 * __uint_as_float(h0 << 16);
      ay += w0 * __uint_as_float(h0 & 0xffff0000u);
    }
  }
  float z0 = ax + bx + (act2 ? bias[2 * lane] : 0.f);
  float z1 = ay + by + (act2 ? bias[2 * lane + 1] : 0.f);
  float mx = act2 ? fmaxf(z0, z1) : -1e30f;
  for (int off = 32; off > 0; off >>= 1) mx = fmaxf(mx, __shfl_xor(mx, off));
  float sm = act2 ? (__expf(z0 - mx) + __expf(z1 - mx)) : 0.f;
  for (int off = 32; off > 0; off >>= 1) sm += __shfl_xor(sm, off);
  float ls = __logf(sm);
  if (act2) {
    float2 r;
    r.x = z0 - mx - ls;
    r.y = z1 - mx - ls;
    *reinterpret_cast<float2*>(out + (size_t)n * NCLASS + 2 * lane) = r;
  }
}

extern "C" void kernel_launch(void* const* d_in, const int* in_sizes, int n_in,
                              void* d_out, int out_size, void* d_ws, size_t ws_size,
                              hipStream_t stream) {
  const float* x   = (const float*)d_in[0];
  const int* edges = (const int*)d_in[1];
  const float* W1  = (const float*)d_in[2];
  const float* al1 = (const float*)d_in[3];
  const float* ar1 = (const float*)d_in[4];
  const float* b1  = (const float*)d_in[5];
  const float* W2  = (const float*)d_in[6];
  const float* al2 = (const float*)d_in[7];
  const float* ar2 = (const float*)d_in[8];
  const float* b2  = (const float*)d_in[9];
  const float* W3  = (const float*)d_in[10];
  const float* al3 = (const float*)d_in[11];
  const float* ar3 = (const float*)d_in[12];
  const float* b3  = (const float*)d_in[13];
  float* out = (float*)d_out;

  const size_t N = N_NODES, E = N_EDGES;
  float* el  = (float*)d_ws;             // [N,4]
  float* er  = el + N * 4;               // [N,4]
  float* el3 = er + N * 4;               // [N]
  float* er3 = el3 + N;                  // [N]
  __hip_bfloat16* xb = (__hip_bfloat16*)(er3 + N);  // [N,256]
  __hip_bfloat16* hb = xb + N * 256;     // [N,256]
  __hip_bfloat16* ob = hb + N * 256;     // [N,256]
  __hip_bfloat16* h3b = ob + N * 256;    // [N,64]
  __hip_bfloat16* WT1 = h3b + N * 64;    // [256,256]
  __hip_bfloat16* WT2 = WT1 + 256 * 256; // [256,256]
  __hip_bfloat16* WT3 = WT2 + 256 * 256; // [64,256]
  int* rowp   = (int*)(WT3 + 64 * 256);  // [N+1]
  int* cursor = rowp + (N + 1);          // [N]
  int* srcs   = cursor + N;              // [E]
  int* deg    = srcs + E;                // [N]
  int* bsums  = deg + N;                 // [256]
  int* flag   = bsums + 256;             // [1]

  hipMemsetAsync(deg, 0, N * sizeof(int), stream);
  detect_i64<<<1, 64, 0, stream>>>(edges, flag);
  int eb = (int)((E + 255) / 256);
  count_raw<<<eb, 256, 0, stream>>>(edges, flag, deg);
  int nb = (int)((N + 255) / 256);
  scan_bsum<<<nb, 256, 0, stream>>>(deg, bsums);
  scan_offsets<<<1, 256, 0, stream>>>(bsums, rowp, nb);
  scan_final<<<nb, 256, 0, stream>>>(deg, bsums, rowp, cursor);
  scatter_raw<<<eb, 256, 0, stream>>>(edges, flag, cursor, srcs);

  cast_x<<<(unsigned)(N * 256 / 4 / 256), 256, 0, stream>>>(x, xb);
  prep_w<<<576, 256, 0, stream>>>(W1, W2, W3, WT1, WT2, WT3);

  dim3 gg((unsigned)((N + 127) / 128), 2);  // 391 x 2
  dim3 g3((unsigned)((N + 127) / 128), 1);

  // layer 1
  gemm_gat12<<<gg, 256, 0, stream>>>(xb, WT1, al1, ar1, hb, el, er);
  agg_fused<<<(unsigned)(N / 2), 128, 0, stream>>>(hb, el, er, b1, rowp, srcs, ob);
  // layer 2
  gemm_gat12<<<gg, 256, 0, stream>>>(ob, WT2, al2, ar2, hb, el, er);
  agg_fused<<<(unsigned)(N / 2), 128, 0, stream>>>(hb, el, er, b2, rowp, srcs, ob);
  // layer 3 + fused log_softmax
  gemm_gat3<<<g3, 256, 0, stream>>>(ob, WT3, al3, ar3, h3b, el3, er3);
  agg_cls_fused<<<(unsigned)(N / 2), 128, 0, stream>>>(h3b, el3, er3, b3, rowp, srcs, out);
}

// Round 8
// 477.318 us; speedup vs baseline: 1.0202x; 1.0202x over previous
//
#include <hip/hip_runtime.h>
#include <hip/hip_bf16.h>
#include <math.h>

#define N_NODES 50000
#define N_EDGES 800000
#define NCLASS 40
#define MAXE 64

using f32x4 = __attribute__((ext_vector_type(4))) float;
using s16x8 = __attribute__((ext_vector_type(8))) short;

// ---------------- edge dtype detect ----------------
__global__ void detect_i64(const int* __restrict__ raw, int* __restrict__ flag) {
  int t = threadIdx.x;
  int v = raw[2 * t + 1];
  unsigned long long any = __ballot(v != 0);
  if (t == 0) flag[0] = (any == 0ULL) ? 1 : 0;
}

// ---------------- CSR build: stage compact s32/d32 once, count, scan, scatter --------
__global__ void norm_count(const int* __restrict__ raw, const int* __restrict__ flag,
                           int* __restrict__ s32, int* __restrict__ d32,
                           int* __restrict__ deg) {
  int e = blockIdx.x * blockDim.x + threadIdx.x;
  if (e >= N_EDGES) return;
  int s, d;
  if (flag[0]) {
    s = raw[2 * e];
    d = raw[2 * N_EDGES + 2 * e];
  } else {
    s = raw[e];
    d = raw[N_EDGES + e];
  }
  s32[e] = s;
  d32[e] = d;
  atomicAdd(&deg[d], 1);
}

__global__ void scan_bsum(const int* __restrict__ deg, int* __restrict__ bsums) {
  __shared__ int sm[256];
  int t = threadIdx.x;
  int i = blockIdx.x * 256 + t;
  sm[t] = (i < N_NODES) ? deg[i] : 0;
  __syncthreads();
  for (int off = 128; off > 0; off >>= 1) {
    if (t < off) sm[t] += sm[t + off];
    __syncthreads();
  }
  if (t == 0) bsums[blockIdx.x] = sm[0];
}

__global__ void scan_offsets(int* __restrict__ bsums, int* __restrict__ rowp, int nb) {
  __shared__ int sm[256];
  int t = threadIdx.x;
  int v = (t < nb) ? bsums[t] : 0;
  sm[t] = v;
  __syncthreads();
  for (int off = 1; off < 256; off <<= 1) {
    int add = (t >= off) ? sm[t - off] : 0;
    __syncthreads();
    sm[t] += add;
    __syncthreads();
  }
  if (t < nb) bsums[t] = sm[t] - v;
  if (t == 0) rowp[N_NODES] = N_EDGES;
}

__global__ void scan_final(const int* __restrict__ deg, const int* __restrict__ bsums,
                           int* __restrict__ rowp, int* __restrict__ cursor) {
  __shared__ int sm[256];
  int t = threadIdx.x;
  int i = blockIdx.x * 256 + t;
  int v = (i < N_NODES) ? deg[i] : 0;
  sm[t] = v;
  __syncthreads();
  for (int off = 1; off < 256; off <<= 1) {
    int add = (t >= off) ? sm[t - off] : 0;
    __syncthreads();
    sm[t] += add;
    __syncthreads();
  }
  int excl = sm[t] - v + bsums[blockIdx.x];
  if (i < N_NODES) { rowp[i] = excl; cursor[i] = excl; }
}

__global__ void scatter_edges(const int* __restrict__ s32, const int* __restrict__ d32,
                              int* __restrict__ cursor, int* __restrict__ srcs) {
  int e = blockIdx.x * blockDim.x + threadIdx.x;
  if (e >= N_EDGES) return;
  int d = d32[e];
  int pos = atomicAdd(&cursor[d], 1);
  srcs[pos] = s32[e];
}

// ---------------- weight prep (all three layers in one launch) ----------------
__global__ void prep_w(const float* __restrict__ W1, const float* __restrict__ W2,
                       const float* __restrict__ W3,
                       __hip_bfloat16* __restrict__ WT1, __hip_bfloat16* __restrict__ WT2,
                       __hip_bfloat16* __restrict__ WT3) {
  int b = blockIdx.x, t = threadIdx.x;
  if (b < 256) {
    int id = b * 256 + t;
    int n = id >> 8, k = id & 255;
    WT1[n * 256 + k] = __float2bfloat16(W1[k * 256 + n]);
  } else if (b < 512) {
    int id = (b - 256) * 256 + t;
    int n = id >> 8, k = id & 255;
    WT2[n * 256 + k] = __float2bfloat16(W2[k * 256 + n]);
  } else {
    int id = (b - 512) * 256 + t;
    int n = id >> 8, k = id & 255;
    WT3[n * 256 + k] = (n < NCLASS) ? __float2bfloat16(W3[k * NCLASS + n]) : __float2bfloat16(0.f);
  }
}

__global__ void cast_x(const float* __restrict__ x, __hip_bfloat16* __restrict__ xb) {
  int id = blockIdx.x * 256 + threadIdx.x;
  float4 v = *reinterpret_cast<const float4*>(x + (size_t)id * 4);
  ushort4 u;
  __hip_bfloat16 b;
  b = __float2bfloat16(v.x); u.x = *(unsigned short*)&b;
  b = __float2bfloat16(v.y); u.y = *(unsigned short*)&b;
  b = __float2bfloat16(v.z); u.z = *(unsigned short*)&b;
  b = __float2bfloat16(v.w); u.w = *(unsigned short*)&b;
  *reinterpret_cast<ushort4*>((unsigned short*)xb + (size_t)id * 4) = u;
}

// ---------------- bf16 MFMA GEMM, layers 1-2, fused el/er + bf16-out epilogue ----------
__global__ __launch_bounds__(256) void gemm_gat12(const __hip_bfloat16* __restrict__ A,
                                                  const __hip_bfloat16* __restrict__ WT,
                                                  const float* __restrict__ al,
                                                  const float* __restrict__ ar,
                                                  __hip_bfloat16* __restrict__ hb,
                                                  float* __restrict__ el,
                                                  float* __restrict__ er) {
  constexpr int MREP = 4, NREP = 4;
  __shared__ __align__(16) __hip_bfloat16 As[128][40];
  __shared__ __align__(16) __hip_bfloat16 Bs[128][40];

  int t = threadIdx.x;
  int lane = t & 63, wave = t >> 6;
  int wr = wave >> 1, wc = wave & 1;
  int row0 = blockIdx.x * 128, col0 = blockIdx.y * 128;
  int ln = lane & 15;
  int kc8 = (lane >> 4) * 8;

  f32x4 acc[MREP][NREP];
  const f32x4 fz = {0.f, 0.f, 0.f, 0.f};
#pragma unroll
  for (int m = 0; m < MREP; ++m)
#pragma unroll
    for (int n = 0; n < NREP; ++n) acc[m][n] = fz;

  for (int k0 = 0; k0 < 256; k0 += 32) {
#pragma unroll
    for (int it = 0; it < 2; ++it) {
      int c = t + it * 256;
      int r = c >> 2, kc = (c & 3) * 8;
      int grow = row0 + r;
      f32x4 v = fz;
      if (grow < N_NODES)
        v = *reinterpret_cast<const f32x4*>(A + (size_t)grow * 256 + k0 + kc);
      *reinterpret_cast<f32x4*>(&As[r][kc]) = v;
    }
#pragma unroll
    for (int it = 0; it < 2; ++it) {
      int c = t + it * 256;
      int r = c >> 2, kc = (c & 3) * 8;
      f32x4 v = *reinterpret_cast<const f32x4*>(WT + (size_t)(col0 + r) * 256 + k0 + kc);
      *reinterpret_cast<f32x4*>(&Bs[r][kc]) = v;
    }
    __syncthreads();
    s16x8 af[MREP], bfr[NREP];
#pragma unroll
    for (int m = 0; m < MREP; ++m)
      af[m] = *reinterpret_cast<const s16x8*>(&As[wr * 64 + m * 16 + ln][kc8]);
#pragma unroll
    for (int n = 0; n < NREP; ++n)
      bfr[n] = *reinterpret_cast<const s16x8*>(&Bs[wc * 64 + n * 16 + ln][kc8]);
#pragma unroll
    for (int m = 0; m < MREP; ++m)
#pragma unroll
      for (int n = 0; n < NREP; ++n)
        acc[m][n] = __builtin_amdgcn_mfma_f32_16x16x32_bf16(af[m], bfr[n], acc[m][n], 0, 0, 0);
    __syncthreads();
  }

  int head = blockIdx.y * 2 + wc;
  float alv[NREP], arv[NREP];
#pragma unroll
  for (int n = 0; n < NREP; ++n) {
    int c = head * 64 + n * 16 + ln;
    alv[n] = al[c];
    arv[n] = ar[c];
  }
#pragma unroll
  for (int m = 0; m < MREP; ++m) {
#pragma unroll
    for (int r = 0; r < 4; ++r) {
      int row = row0 + wr * 64 + m * 16 + (lane >> 4) * 4 + r;
      bool ok = row < N_NODES;
      float pl = 0.f, pr = 0.f;
#pragma unroll
      for (int n = 0; n < NREP; ++n) {
        float v = acc[m][n][r];
        pl += v * alv[n];
        pr += v * arv[n];
        if (ok) hb[(size_t)row * 256 + head * 64 + n * 16 + ln] = __float2bfloat16(v);
      }
      for (int off = 1; off < 16; off <<= 1) {
        pl += __shfl_xor(pl, off);
        pr += __shfl_xor(pr, off);
      }
      if (ln == 0 && ok) {
        el[row * 4 + head] = pl;
        er[row * 4 + head] = pr;
      }
    }
  }
}

// ---------------- layer-3 GEMM: fused el/er, bf16 h3 out ----------------
__global__ __launch_bounds__(256) void gemm_gat3(const __hip_bfloat16* __restrict__ A,
                                                 const __hip_bfloat16* __restrict__ WT,
                                                 const float* __restrict__ al,
                                                 const float* __restrict__ ar,
                                                 __hip_bfloat16* __restrict__ h3b,
                                                 float* __restrict__ el3,
                                                 float* __restrict__ er3) {
  constexpr int MREP = 2, NREP = 4;
  __shared__ __align__(16) __hip_bfloat16 As[128][40];
  __shared__ __align__(16) __hip_bfloat16 Bs[64][40];

  int t = threadIdx.x;
  int lane = t & 63, wave = t >> 6;
  int row0 = blockIdx.x * 128;
  int ln = lane & 15;
  int kc8 = (lane >> 4) * 8;

  f32x4 acc[MREP][NREP];
  const f32x4 fz = {0.f, 0.f, 0.f, 0.f};
#pragma unroll
  for (int m = 0; m < MREP; ++m)
#pragma unroll
    for (int n = 0; n < NREP; ++n) acc[m][n] = fz;

  for (int k0 = 0; k0 < 256; k0 += 32) {
#pragma unroll
    for (int it = 0; it < 2; ++it) {
      int c = t + it * 256;
      int r = c >> 2, kc = (c & 3) * 8;
      int grow = row0 + r;
      f32x4 v = fz;
      if (grow < N_NODES)
        v = *reinterpret_cast<const f32x4*>(A + (size_t)grow * 256 + k0 + kc);
      *reinterpret_cast<f32x4*>(&As[r][kc]) = v;
    }
    {
      int c = t;
      int r = c >> 2, kc = (c & 3) * 8;
      f32x4 v = *reinterpret_cast<const f32x4*>(WT + (size_t)r * 256 + k0 + kc);
      *reinterpret_cast<f32x4*>(&Bs[r][kc]) = v;
    }
    __syncthreads();
    s16x8 af[MREP], bfr[NREP];
#pragma unroll
    for (int m = 0; m < MREP; ++m)
      af[m] = *reinterpret_cast<const s16x8*>(&As[wave * 32 + m * 16 + ln][kc8]);
#pragma unroll
    for (int n = 0; n < NREP; ++n)
      bfr[n] = *reinterpret_cast<const s16x8*>(&Bs[n * 16 + ln][kc8]);
#pragma unroll
    for (int m = 0; m < MREP; ++m)
#pragma unroll
      for (int n = 0; n < NREP; ++n)
        acc[m][n] = __builtin_amdgcn_mfma_f32_16x16x32_bf16(af[m], bfr[n], acc[m][n], 0, 0, 0);
    __syncthreads();
  }

  float alv[NREP], arv[NREP];
#pragma unroll
  for (int n = 0; n < NREP; ++n) {
    int c = n * 16 + ln;
    alv[n] = (c < NCLASS) ? al[c] : 0.f;
    arv[n] = (c < NCLASS) ? ar[c] : 0.f;
  }
#pragma unroll
  for (int m = 0; m < MREP; ++m) {
#pragma unroll
    for (int r = 0; r < 4; ++r) {
      int row = row0 + wave * 32 + m * 16 + (lane >> 4) * 4 + r;
      bool ok = row < N_NODES;
      float pl = 0.f, pr = 0.f;
#pragma unroll
      for (int n = 0; n < NREP; ++n) {
        float v = acc[m][n][r];
        pl += v * alv[n];
        pr += v * arv[n];
        if (ok) h3b[(size_t)row * 64 + n * 16 + ln] = __float2bfloat16(v);
      }
      for (int off = 1; off < 16; off <<= 1) {
        pl += __shfl_xor(pl, off);
        pr += __shfl_xor(pr, off);
      }
      if (ln == 0 && ok) {
        el3[row] = pl;
        er3[row] = pr;
      }
    }
  }
}

// ---------------- fused stats + gather, layers 1-2: 2 waves/block, 1 node/wave -------
// Two-phase softmax: plain-max butterfly (no expf), per-lane exp of own edges,
// sum butterfly; LDS holds UNNORMALIZED w; normalization folded into epilogue.
__global__ __launch_bounds__(128) void agg_fused(const __hip_bfloat16* __restrict__ hb,
                                                 const float* __restrict__ el,
                                                 const float* __restrict__ er,
                                                 const float* __restrict__ bias,
                                                 const int* __restrict__ rowp,
                                                 const int* __restrict__ srcs,
                                                 __hip_bfloat16* __restrict__ ob) {
  __shared__ float eld[2][MAXE * 4];
  int wv = threadIdx.x >> 6, lane = threadIdx.x & 63;
  int n = blockIdx.x * 2 + wv;
  float* ew = eld[wv];
  int i0 = rowp[n], deg = rowp[n + 1] - i0;
  float4 ern4 = *reinterpret_cast<const float4*>(er + (size_t)n * 4);
  float m0 = -1e30f, m1 = -1e30f, m2 = -1e30f, m3 = -1e30f;
  float e0 = 0.f, e1 = 0.f, e2 = 0.f, e3 = 0.f;
  for (int j = lane; j < deg; j += 64) {
    int s = srcs[i0 + j];
    float4 e4 = *reinterpret_cast<const float4*>(el + (size_t)s * 4);
    e0 = e4.x + ern4.x; e0 = (e0 >= 0.f) ? e0 : 0.2f * e0;
    e1 = e4.y + ern4.y; e1 = (e1 >= 0.f) ? e1 : 0.2f * e1;
    e2 = e4.z + ern4.z; e2 = (e2 >= 0.f) ? e2 : 0.2f * e2;
    e3 = e4.w + ern4.w; e3 = (e3 >= 0.f) ? e3 : 0.2f * e3;
    if (j < MAXE)
      *reinterpret_cast<float4*>(&ew[j * 4]) = make_float4(e0, e1, e2, e3);
    m0 = fmaxf(m0, e0);
    m1 = fmaxf(m1, e1);
    m2 = fmaxf(m2, e2);
    m3 = fmaxf(m3, e3);
  }
#pragma unroll
  for (int off = 1; off < 64; off <<= 1) {
    m0 = fmaxf(m0, __shfl_xor(m0, off));
    m1 = fmaxf(m1, __shfl_xor(m1, off));
    m2 = fmaxf(m2, __shfl_xor(m2, off));
    m3 = fmaxf(m3, __shfl_xor(m3, off));
  }
  float l0 = 0.f, l1 = 0.f, l2 = 0.f, l3 = 0.f;
  if (deg <= 64) {
    if (lane < deg) {
      float w0 = __expf(e0 - m0), w1 = __expf(e1 - m1);
      float w2 = __expf(e2 - m2), w3 = __expf(e3 - m3);
      *reinterpret_cast<float4*>(&ew[lane * 4]) = make_float4(w0, w1, w2, w3);
      l0 = w0; l1 = w1; l2 = w2; l3 = w3;
    }
  } else {
    for (int j = lane; j < deg; j += 64) {
      float a0, a1, a2, a3;
      if (j < MAXE) {
        float4 q = *reinterpret_cast<const float4*>(&ew[j * 4]);
        a0 = q.x; a1 = q.y; a2 = q.z; a3 = q.w;
      } else {
        int s = srcs[i0 + j];
        float4 q = *reinterpret_cast<const float4*>(el + (size_t)s * 4);
        a0 = q.x + ern4.x; a0 = (a0 >= 0.f) ? a0 : 0.2f * a0;
        a1 = q.y + ern4.y; a1 = (a1 >= 0.f) ? a1 : 0.2f * a1;
        a2 = q.z + ern4.z; a2 = (a2 >= 0.f) ? a2 : 0.2f * a2;
        a3 = q.w + ern4.w; a3 = (a3 >= 0.f) ? a3 : 0.2f * a3;
      }
      float w0 = __expf(a0 - m0), w1 = __expf(a1 - m1);
      float w2 = __expf(a2 - m2), w3 = __expf(a3 - m3);
      if (j < MAXE)
        *reinterpret_cast<float4*>(&ew[j * 4]) = make_float4(w0, w1, w2, w3);
      l0 += w0; l1 += w1; l2 += w2; l3 += w3;
    }
  }
#pragma unroll
  for (int off = 1; off < 64; off <<= 1) {
    l0 += __shfl_xor(l0, off);
    l1 += __shfl_xor(l1, off);
    l2 += __shfl_xor(l2, off);
    l3 += __shfl_xor(l3, off);
  }
  float inv0 = (l0 > 0.f) ? (1.f / l0) : 0.f;
  float inv1 = (l1 > 0.f) ? (1.f / l1) : 0.f;
  float inv2 = (l2 > 0.f) ? (1.f / l2) : 0.f;
  float inv3 = (l3 > 0.f) ? (1.f / l3) : 0.f;
  __syncthreads();
  // pass B: lane handles dims 4*lane..4*lane+3 (head = lane>>4); weights unnormalized
  int head = lane >> 4;
  float mh = (head == 0) ? m0 : (head == 1) ? m1 : (head == 2) ? m2 : m3;
  float ivh = (head == 0) ? inv0 : (head == 1) ? inv1 : (head == 2) ? inv2 : inv3;
  float ernh = (head == 0) ? ern4.x : (head == 1) ? ern4.y : (head == 2) ? ern4.z : ern4.w;
  const uint2* hp = (const uint2*)hb;
  float4 A = make_float4(0.f, 0.f, 0.f, 0.f);
  float4 B = make_float4(0.f, 0.f, 0.f, 0.f);
  float4 C = make_float4(0.f, 0.f, 0.f, 0.f);
  float4 D = make_float4(0.f, 0.f, 0.f, 0.f);
  int j = 0;
  for (; j + 3 < deg; j += 4) {
    int s0 = srcs[i0 + j], s1 = srcs[i0 + j + 1], s2 = srcs[i0 + j + 2], s3 = srcs[i0 + j + 3];
    float w0, w1, w2, w3;
    if (j + 3 < MAXE) {
      w0 = ew[(j + 0) * 4 + head];
      w1 = ew[(j + 1) * 4 + head];
      w2 = ew[(j + 2) * 4 + head];
      w3 = ew[(j + 3) * 4 + head];
    } else {
      float q0 = el[s0 * 4 + head] + ernh; q0 = (q0 >= 0.f) ? q0 : 0.2f * q0;
      float q1 = el[s1 * 4 + head] + ernh; q1 = (q1 >= 0.f) ? q1 : 0.2f * q1;
      float q2 = el[s2 * 4 + head] + ernh; q2 = (q2 >= 0.f) ? q2 : 0.2f * q2;
      float q3 = el[s3 * 4 + head] + ernh; q3 = (q3 >= 0.f) ? q3 : 0.2f * q3;
      w0 = __expf(q0 - mh);
      w1 = __expf(q1 - mh);
      w2 = __expf(q2 - mh);
      w3 = __expf(q3 - mh);
    }
    uint2 h0 = hp[(size_t)s0 * 64 + lane];
    uint2 h1 = hp[(size_t)s1 * 64 + lane];
    uint2 h2 = hp[(size_t)s2 * 64 + lane];
    uint2 h3v = hp[(size_t)s3 * 64 + lane];
    A.x += w0 * __uint_as_float(h0.x << 16);
    A.y += w0 * __uint_as_float(h0.x & 0xffff0000u);
    A.z += w0 * __uint_as_float(h0.y << 16);
    A.w += w0 * __uint_as_float(h0.y & 0xffff0000u);
    B.x += w1 * __uint_as_float(h1.x << 16);
    B.y += w1 * __uint_as_float(h1.x & 0xffff0000u);
    B.z += w1 * __uint_as_float(h1.y << 16);
    B.w += w1 * __uint_as_float(h1.y & 0xffff0000u);
    C.x += w2 * __uint_as_float(h2.x << 16);
    C.y += w2 * __uint_as_float(h2.x & 0xffff0000u);
    C.z += w2 * __uint_as_float(h2.y << 16);
    C.w += w2 * __uint_as_float(h2.y & 0xffff0000u);
    D.x += w3 * __uint_as_float(h3v.x << 16);
    D.y += w3 * __uint_as_float(h3v.x & 0xffff0000u);
    D.z += w3 * __uint_as_float(h3v.y << 16);
    D.w += w3 * __uint_as_float(h3v.y & 0xffff0000u);
  }
  for (; j < deg; ++j) {
    int s0 = srcs[i0 + j];
    float w0;
    if (j < MAXE) {
      w0 = ew[j * 4 + head];
    } else {
      float q0 = el[s0 * 4 + head] + ernh; q0 = (q0 >= 0.f) ? q0 : 0.2f * q0;
      w0 = __expf(q0 - mh);
    }
    uint2 h0 = hp[(size_t)s0 * 64 + lane];
    A.x += w0 * __uint_as_float(h0.x << 16);
    A.y += w0 * __uint_as_float(h0.x & 0xffff0000u);
    A.z += w0 * __uint_as_float(h0.y << 16);
    A.w += w0 * __uint_as_float(h0.y & 0xffff0000u);
  }
  float4 b4 = *reinterpret_cast<const float4*>(bias + (size_t)lane * 4);
  float r0 = ((A.x + B.x) + (C.x + D.x)) * ivh + b4.x;
  float r1 = ((A.y + B.y) + (C.y + D.y)) * ivh + b4.y;
  float r2 = ((A.z + B.z) + (C.z + D.z)) * ivh + b4.z;
  float r3 = ((A.w + B.w) + (C.w + D.w)) * ivh + b4.w;
  r0 = (r0 > 0.f) ? r0 : (__expf(r0) - 1.f);
  r1 = (r1 > 0.f) ? r1 : (__expf(r1) - 1.f);
  r2 = (r2 > 0.f) ? r2 : (__expf(r2) - 1.f);
  r3 = (r3 > 0.f) ? r3 : (__expf(r3) - 1.f);
  __hip_bfloat16 q0 = __float2bfloat16(r0), q1 = __float2bfloat16(r1);
  __hip_bfloat16 q2 = __float2bfloat16(r2), q3 = __float2bfloat16(r3);
  uint2 o;
  o.x = (unsigned int)(*(unsigned short*)&q0) | ((unsigned int)(*(unsigned short*)&q1) << 16);
  o.y = (unsigned int)(*(unsigned short*)&q2) | ((unsigned int)(*(unsigned short*)&q3) << 16);
  ((uint2*)ob)[(size_t)n * 64 + lane] = o;
}

// ---------------- layer 3: fused stats + gather + bias + log_softmax (2 nodes/block) --
__global__ __launch_bounds__(128) void agg_cls_fused(const __hip_bfloat16* __restrict__ h3b,
                                                     const float* __restrict__ el3,
                                                     const float* __restrict__ er3,
                                                     const float* __restrict__ bias,
                                                     const int* __restrict__ rowp,
                                                     const int* __restrict__ srcs,
                                                     float* __restrict__ out) {
  __shared__ float eldc[2][MAXE];
  int wv = threadIdx.x >> 6, lane = threadIdx.x & 63;
  int n = blockIdx.x * 2 + wv;
  float* ec = eldc[wv];
  int i0 = rowp[n], deg = rowp[n + 1] - i0;
  float ern = er3[n];
  float m = -1e30f, e = 0.f;
  for (int j = lane; j < deg; j += 64) {
    int s = srcs[i0 + j];
    e = el3[s] + ern;
    e = (e >= 0.f) ? e : 0.2f * e;
    if (j < MAXE) ec[j] = e;
    m = fmaxf(m, e);
  }
#pragma unroll
  for (int off = 1; off < 64; off <<= 1) m = fmaxf(m, __shfl_xor(m, off));
  float l = 0.f;
  if (deg <= 64) {
    if (lane < deg) {
      float w = __expf(e - m);
      ec[lane] = w;
      l = w;
    }
  } else {
    for (int j = lane; j < deg; j += 64) {
      float a;
      if (j < MAXE) {
        a = ec[j];
      } else {
        int s = srcs[i0 + j];
        a = el3[s] + ern;
        a = (a >= 0.f) ? a : 0.2f * a;
      }
      float w = __expf(a - m);
      if (j < MAXE) ec[j] = w;
      l += w;
    }
  }
#pragma unroll
  for (int off = 1; off < 64; off <<= 1) l += __shfl_xor(l, off);
  float inv = (l > 0.f) ? (1.f / l) : 0.f;
  __syncthreads();
  bool act2 = lane < ((NCLASS + 1) / 2);  // lane < 20, dims {2*lane, 2*lane+1}
  const unsigned int* hp3 = (const unsigned int*)h3b;
  float ax = 0.f, ay = 0.f, bx = 0.f, by = 0.f;
  int j = 0;
  for (; j + 1 < deg; j += 2) {
    int s0 = srcs[i0 + j], s1 = srcs[i0 + j + 1];
    float w0, w1;
    if (j + 1 < MAXE) {
      w0 = ec[j];
      w1 = ec[j + 1];
    } else {
      float q0 = el3[s0] + ern; q0 = (q0 >= 0.f) ? q0 : 0.2f * q0;
      float q1 = el3[s1] + ern; q1 = (q1 >= 0.f) ? q1 : 0.2f * q1;
      w0 = __expf(q0 - m);
      w1 = __expf(q1 - m);
    }
    if (act2) {
      unsigned int h0 = hp3[(size_t)s0 * 32 + lane];
      unsigned int h1 = hp3[(size_t)s1 * 32 + lane];
      ax += w0 * __uint_as_float(h0 << 16);
      ay += w0 * __uint_as_float(h0 & 0xffff0000u);
      bx += w1 * __uint_as_float(h1 << 16);
      by += w1 * __uint_as_float(h1 & 0xffff0000u);
    }
  }
  if (j < deg) {
    int s0 = srcs[i0 + j];
    float w0;
    if (j < MAXE) {
      w0 = ec[j];
    } else {
      float q0 = el3[s0] + ern; q0 = (q0 >= 0.f) ? q0 : 0.2f * q0;
      w0 = __expf(q0 - m);
    }
    if (act2) {
      unsigned int h0 = hp3[(size_t)s0 * 32 + lane];
      ax += w0 * __uint_as_float(h0 << 16);
      ay += w0 * __uint_as_float(h0 & 0xffff0000u);
    }
  }
  float z0 = (ax + bx) * inv + (act2 ? bias[2 * lane] : 0.f);
  float z1 = (ay + by) * inv + (act2 ? bias[2 * lane + 1] : 0.f);
  float mx = act2 ? fmaxf(z0, z1) : -1e30f;
  for (int off = 32; off > 0; off >>= 1) mx = fmaxf(mx, __shfl_xor(mx, off));
  float sm = act2 ? (__expf(z0 - mx) + __expf(z1 - mx)) : 0.f;
  for (int off = 32; off > 0; off >>= 1) sm += __shfl_xor(sm, off);
  float ls = __logf(sm);
  if (act2) {
    float2 r;
    r.x = z0 - mx - ls;
    r.y = z1 - mx - ls;
    *reinterpret_cast<float2*>(out + (size_t)n * NCLASS + 2 * lane) = r;
  }
}

extern "C" void kernel_launch(void* const* d_in, const int* in_sizes, int n_in,
                              void* d_out, int out_size, void* d_ws, size_t ws_size,
                              hipStream_t stream) {
  const float* x   = (const float*)d_in[0];
  const int* edges = (const int*)d_in[1];
  const float* W1  = (const float*)d_in[2];
  const float* al1 = (const float*)d_in[3];
  const float* ar1 = (const float*)d_in[4];
  const float* b1  = (const float*)d_in[5];
  const float* W2  = (const float*)d_in[6];
  const float* al2 = (const float*)d_in[7];
  const float* ar2 = (const float*)d_in[8];
  const float* b2  = (const float*)d_in[9];
  const float* W3  = (const float*)d_in[10];
  const float* al3 = (const float*)d_in[11];
  const float* ar3 = (const float*)d_in[12];
  const float* b3  = (const float*)d_in[13];
  float* out = (float*)d_out;

  const size_t N = N_NODES, E = N_EDGES;
  float* el  = (float*)d_ws;             // [N,4]
  float* er  = el + N * 4;               // [N,4]
  float* el3 = er + N * 4;               // [N]
  float* er3 = el3 + N;                  // [N]
  __hip_bfloat16* xb = (__hip_bfloat16*)(er3 + N);  // [N,256]
  __hip_bfloat16* hb = xb + N * 256;     // [N,256]
  __hip_bfloat16* ob = hb + N * 256;     // [N,256]
  __hip_bfloat16* h3b = ob + N * 256;    // [N,64]
  __hip_bfloat16* WT1 = h3b + N * 64;    // [256,256]
  __hip_bfloat16* WT2 = WT1 + 256 * 256; // [256,256]
  __hip_bfloat16* WT3 = WT2 + 256 * 256; // [64,256]
  int* rowp   = (int*)(WT3 + 64 * 256);  // [N+1]
  int* cursor = rowp + (N + 1);          // [N]
  int* srcs   = cursor + N;              // [E]
  int* deg    = srcs + E;                // [N]
  int* bsums  = deg + N;                 // [256]
  int* s32    = bsums + 256;             // [E]
  int* d32    = s32 + E;                 // [E]
  int* flag   = d32 + E;                 // [1]

  hipMemsetAsync(deg, 0, N * sizeof(int), stream);
  detect_i64<<<1, 64, 0, stream>>>(edges, flag);
  int eb = (int)((E + 255) / 256);
  norm_count<<<eb, 256, 0, stream>>>(edges, flag, s32, d32, deg);
  int nb = (int)((N + 255) / 256);
  scan_bsum<<<nb, 256, 0, stream>>>(deg, bsums);
  scan_offsets<<<1, 256, 0, stream>>>(bsums, rowp, nb);
  scan_final<<<nb, 256, 0, stream>>>(deg, bsums, rowp, cursor);
  scatter_edges<<<eb, 256, 0, stream>>>(s32, d32, cursor, srcs);

  cast_x<<<(unsigned)(N * 256 / 4 / 256), 256, 0, stream>>>(x, xb);
  prep_w<<<576, 256, 0, stream>>>(W1, W2, W3, WT1, WT2, WT3);

  dim3 gg((unsigned)((N + 127) / 128), 2);  // 391 x 2
  dim3 g3((unsigned)((N + 127) / 128), 1);

  // layer 1
  gemm_gat12<<<gg, 256, 0, stream>>>(xb, WT1, al1, ar1, hb, el, er);
  agg_fused<<<(unsigned)(N / 2), 128, 0, stream>>>(hb, el, er, b1, rowp, srcs, ob);
  // layer 2
  gemm_gat12<<<gg, 256, 0, stream>>>(ob, WT2, al2, ar2, hb, el, er);
  agg_fused<<<(unsigned)(N / 2), 128, 0, stream>>>(hb, el, er, b2, rowp, srcs, ob);
  // layer 3 + fused log_softmax
  gemm_gat3<<<g3, 256, 0, stream>>>(ob, WT3, al3, ar3, h3b, el3, er3);
  agg_cls_fused<<<(unsigned)(N / 2), 128, 0, stream>>>(h3b, el3, er3, b3, rowp, srcs, out);
}

// Round 10
// 469.091 us; speedup vs baseline: 1.0381x; 1.0175x over previous
//
#include <hip/hip_runtime.h>
#include <hip/hip_bf16.h>
#include <math.h>

#define N_NODES 50000
#define N_EDGES 800000
#define NCLASS 40
#define MAXE 64

using f32x4 = __attribute__((ext_vector_type(4))) float;
using s16x8 = __attribute__((ext_vector_type(8))) short;

__device__ __forceinline__ float bflo(unsigned int u) { return __uint_as_float(u << 16); }
__device__ __forceinline__ float bfhi(unsigned int u) { return __uint_as_float(u & 0xffff0000u); }

// ---------------- edge dtype detect ----------------
__global__ void detect_i64(const int* __restrict__ raw, int* __restrict__ flag) {
  int t = threadIdx.x;
  int v = raw[2 * t + 1];
  unsigned long long any = __ballot(v != 0);
  if (t == 0) flag[0] = (any == 0ULL) ? 1 : 0;
}

// ---------------- CSR build: stage compact s32/d32 once, count, scan, scatter --------
__global__ void norm_count(const int* __restrict__ raw, const int* __restrict__ flag,
                           int* __restrict__ s32, int* __restrict__ d32,
                           int* __restrict__ deg) {
  int e = blockIdx.x * blockDim.x + threadIdx.x;
  if (e >= N_EDGES) return;
  int s, d;
  if (flag[0]) {
    s = raw[2 * e];
    d = raw[2 * N_EDGES + 2 * e];
  } else {
    s = raw[e];
    d = raw[N_EDGES + e];
  }
  s32[e] = s;
  d32[e] = d;
  atomicAdd(&deg[d], 1);
}

__global__ void scan_bsum(const int* __restrict__ deg, int* __restrict__ bsums) {
  __shared__ int sm[256];
  int t = threadIdx.x;
  int i = blockIdx.x * 256 + t;
  sm[t] = (i < N_NODES) ? deg[i] : 0;
  __syncthreads();
  for (int off = 128; off > 0; off >>= 1) {
    if (t < off) sm[t] += sm[t + off];
    __syncthreads();
  }
  if (t == 0) bsums[blockIdx.x] = sm[0];
}

__global__ void scan_offsets(int* __restrict__ bsums, int* __restrict__ rowp, int nb) {
  __shared__ int sm[256];
  int t = threadIdx.x;
  int v = (t < nb) ? bsums[t] : 0;
  sm[t] = v;
  __syncthreads();
  for (int off = 1; off < 256; off <<= 1) {
    int add = (t >= off) ? sm[t - off] : 0;
    __syncthreads();
    sm[t] += add;
    __syncthreads();
  }
  if (t < nb) bsums[t] = sm[t] - v;
  if (t == 0) rowp[N_NODES] = N_EDGES;
}

__global__ void scan_final(const int* __restrict__ deg, const int* __restrict__ bsums,
                           int* __restrict__ rowp, int* __restrict__ cursor) {
  __shared__ int sm[256];
  int t = threadIdx.x;
  int i = blockIdx.x * 256 + t;
  int v = (i < N_NODES) ? deg[i] : 0;
  sm[t] = v;
  __syncthreads();
  for (int off = 1; off < 256; off <<= 1) {
    int add = (t >= off) ? sm[t - off] : 0;
    __syncthreads();
    sm[t] += add;
    __syncthreads();
  }
  int excl = sm[t] - v + bsums[blockIdx.x];
  if (i < N_NODES) { rowp[i] = excl; cursor[i] = excl; }
}

__global__ void scatter_edges(const int* __restrict__ s32, const int* __restrict__ d32,
                              int* __restrict__ cursor, int* __restrict__ srcs) {
  int e = blockIdx.x * blockDim.x + threadIdx.x;
  if (e >= N_EDGES) return;
  int d = d32[e];
  int pos = atomicAdd(&cursor[d], 1);
  srcs[pos] = s32[e];
}

// ---------------- weight prep (all three layers in one launch) ----------------
__global__ void prep_w(const float* __restrict__ W1, const float* __restrict__ W2,
                       const float* __restrict__ W3,
                       __hip_bfloat16* __restrict__ WT1, __hip_bfloat16* __restrict__ WT2,
                       __hip_bfloat16* __restrict__ WT3) {
  int b = blockIdx.x, t = threadIdx.x;
  if (b < 256) {
    int id = b * 256 + t;
    int n = id >> 8, k = id & 255;
    WT1[n * 256 + k] = __float2bfloat16(W1[k * 256 + n]);
  } else if (b < 512) {
    int id = (b - 256) * 256 + t;
    int n = id >> 8, k = id & 255;
    WT2[n * 256 + k] = __float2bfloat16(W2[k * 256 + n]);
  } else {
    int id = (b - 512) * 256 + t;
    int n = id >> 8, k = id & 255;
    WT3[n * 256 + k] = (n < NCLASS) ? __float2bfloat16(W3[k * NCLASS + n]) : __float2bfloat16(0.f);
  }
}

__global__ void cast_x(const float* __restrict__ x, __hip_bfloat16* __restrict__ xb) {
  int id = blockIdx.x * 256 + threadIdx.x;
  float4 v = *reinterpret_cast<const float4*>(x + (size_t)id * 4);
  ushort4 u;
  __hip_bfloat16 b;
  b = __float2bfloat16(v.x); u.x = *(unsigned short*)&b;
  b = __float2bfloat16(v.y); u.y = *(unsigned short*)&b;
  b = __float2bfloat16(v.z); u.z = *(unsigned short*)&b;
  b = __float2bfloat16(v.w); u.w = *(unsigned short*)&b;
  *reinterpret_cast<ushort4*>((unsigned short*)xb + (size_t)id * 4) = u;
}

// ---------------- bf16 MFMA GEMM, layers 1-2, fused el/er + bf16-out epilogue ----------
__global__ __launch_bounds__(256) void gemm_gat12(const __hip_bfloat16* __restrict__ A,
                                                  const __hip_bfloat16* __restrict__ WT,
                                                  const float* __restrict__ al,
                                                  const float* __restrict__ ar,
                                                  __hip_bfloat16* __restrict__ hb,
                                                  float* __restrict__ el,
                                                  float* __restrict__ er) {
  constexpr int MREP = 4, NREP = 4;
  __shared__ __align__(16) __hip_bfloat16 As[128][40];
  __shared__ __align__(16) __hip_bfloat16 Bs[128][40];

  int t = threadIdx.x;
  int lane = t & 63, wave = t >> 6;
  int wr = wave >> 1, wc = wave & 1;
  int row0 = blockIdx.x * 128, col0 = blockIdx.y * 128;
  int ln = lane & 15;
  int kc8 = (lane >> 4) * 8;

  f32x4 acc[MREP][NREP];
  const f32x4 fz = {0.f, 0.f, 0.f, 0.f};
#pragma unroll
  for (int m = 0; m < MREP; ++m)
#pragma unroll
    for (int n = 0; n < NREP; ++n) acc[m][n] = fz;

  for (int k0 = 0; k0 < 256; k0 += 32) {
#pragma unroll
    for (int it = 0; it < 2; ++it) {
      int c = t + it * 256;
      int r = c >> 2, kc = (c & 3) * 8;
      int grow = row0 + r;
      f32x4 v = fz;
      if (grow < N_NODES)
        v = *reinterpret_cast<const f32x4*>(A + (size_t)grow * 256 + k0 + kc);
      *reinterpret_cast<f32x4*>(&As[r][kc]) = v;
    }
#pragma unroll
    for (int it = 0; it < 2; ++it) {
      int c = t + it * 256;
      int r = c >> 2, kc = (c & 3) * 8;
      f32x4 v = *reinterpret_cast<const f32x4*>(WT + (size_t)(col0 + r) * 256 + k0 + kc);
      *reinterpret_cast<f32x4*>(&Bs[r][kc]) = v;
    }
    __syncthreads();
    s16x8 af[MREP], bfr[NREP];
#pragma unroll
    for (int m = 0; m < MREP; ++m)
      af[m] = *reinterpret_cast<const s16x8*>(&As[wr * 64 + m * 16 + ln][kc8]);
#pragma unroll
    for (int n = 0; n < NREP; ++n)
      bfr[n] = *reinterpret_cast<const s16x8*>(&Bs[wc * 64 + n * 16 + ln][kc8]);
#pragma unroll
    for (int m = 0; m < MREP; ++m)
#pragma unroll
      for (int n = 0; n < NREP; ++n)
        acc[m][n] = __builtin_amdgcn_mfma_f32_16x16x32_bf16(af[m], bfr[n], acc[m][n], 0, 0, 0);
    __syncthreads();
  }

  int head = blockIdx.y * 2 + wc;
  float alv[NREP], arv[NREP];
#pragma unroll
  for (int n = 0; n < NREP; ++n) {
    int c = head * 64 + n * 16 + ln;
    alv[n] = al[c];
    arv[n] = ar[c];
  }
#pragma unroll
  for (int m = 0; m < MREP; ++m) {
#pragma unroll
    for (int r = 0; r < 4; ++r) {
      int row = row0 + wr * 64 + m * 16 + (lane >> 4) * 4 + r;
      bool ok = row < N_NODES;
      float pl = 0.f, pr = 0.f;
#pragma unroll
      for (int n = 0; n < NREP; ++n) {
        float v = acc[m][n][r];
        pl += v * alv[n];
        pr += v * arv[n];
        if (ok) hb[(size_t)row * 256 + head * 64 + n * 16 + ln] = __float2bfloat16(v);
      }
      for (int off = 1; off < 16; off <<= 1) {
        pl += __shfl_xor(pl, off);
        pr += __shfl_xor(pr, off);
      }
      if (ln == 0 && ok) {
        el[row * 4 + head] = pl;
        er[row * 4 + head] = pr;
      }
    }
  }
}

// ---------------- layer-3 GEMM: fused el/er, bf16 h3 out ----------------
__global__ __launch_bounds__(256) void gemm_gat3(const __hip_bfloat16* __restrict__ A,
                                                 const __hip_bfloat16* __restrict__ WT,
                                                 const float* __restrict__ al,
                                                 const float* __restrict__ ar,
                                                 __hip_bfloat16* __restrict__ h3b,
                                                 float* __restrict__ el3,
                                                 float* __restrict__ er3) {
  constexpr int MREP = 2, NREP = 4;
  __shared__ __align__(16) __hip_bfloat16 As[128][40];
  __shared__ __align__(16) __hip_bfloat16 Bs[64][40];

  int t = threadIdx.x;
  int lane = t & 63, wave = t >> 6;
  int row0 = blockIdx.x * 128;
  int ln = lane & 15;
  int kc8 = (lane >> 4) * 8;

  f32x4 acc[MREP][NREP];
  const f32x4 fz = {0.f, 0.f, 0.f, 0.f};
#pragma unroll
  for (int m = 0; m < MREP; ++m)
#pragma unroll
    for (int n = 0; n < NREP; ++n) acc[m][n] = fz;

  for (int k0 = 0; k0 < 256; k0 += 32) {
#pragma unroll
    for (int it = 0; it < 2; ++it) {
      int c = t + it * 256;
      int r = c >> 2, kc = (c & 3) * 8;
      int grow = row0 + r;
      f32x4 v = fz;
      if (grow < N_NODES)
        v = *reinterpret_cast<const f32x4*>(A + (size_t)grow * 256 + k0 + kc);
      *reinterpret_cast<f32x4*>(&As[r][kc]) = v;
    }
    {
      int c = t;
      int r = c >> 2, kc = (c & 3) * 8;
      f32x4 v = *reinterpret_cast<const f32x4*>(WT + (size_t)r * 256 + k0 + kc);
      *reinterpret_cast<f32x4*>(&Bs[r][kc]) = v;
    }
    __syncthreads();
    s16x8 af[MREP], bfr[NREP];
#pragma unroll
    for (int m = 0; m < MREP; ++m)
      af[m] = *reinterpret_cast<const s16x8*>(&As[wave * 32 + m * 16 + ln][kc8]);
#pragma unroll
    for (int n = 0; n < NREP; ++n)
      bfr[n] = *reinterpret_cast<const s16x8*>(&Bs[n * 16 + ln][kc8]);
#pragma unroll
    for (int m = 0; m < MREP; ++m)
#pragma unroll
      for (int n = 0; n < NREP; ++n)
        acc[m][n] = __builtin_amdgcn_mfma_f32_16x16x32_bf16(af[m], bfr[n], acc[m][n], 0, 0, 0);
    __syncthreads();
  }

  float alv[NREP], arv[NREP];
#pragma unroll
  for (int n = 0; n < NREP; ++n) {
    int c = n * 16 + ln;
    alv[n] = (c < NCLASS) ? al[c] : 0.f;
    arv[n] = (c < NCLASS) ? ar[c] : 0.f;
  }
#pragma unroll
  for (int m = 0; m < MREP; ++m) {
#pragma unroll
    for (int r = 0; r < 4; ++r) {
      int row = row0 + wave * 32 + m * 16 + (lane >> 4) * 4 + r;
      bool ok = row < N_NODES;
      float pl = 0.f, pr = 0.f;
#pragma unroll
      for (int n = 0; n < NREP; ++n) {
        float v = acc[m][n][r];
        pl += v * alv[n];
        pr += v * arv[n];
        if (ok) h3b[(size_t)row * 64 + n * 16 + ln] = __float2bfloat16(v);
      }
      for (int off = 1; off < 16; off <<= 1) {
        pl += __shfl_xor(pl, off);
        pr += __shfl_xor(pr, off);
      }
      if (ln == 0 && ok) {
        el3[row] = pl;
        er3[row] = pr;
      }
    }
  }
}

// ---------------- fused stats + gather, layers 1-2: 2 waves/block, 1 node/wave -------
// Pass A: two-phase softmax (max butterfly, per-lane exp, sum butterfly), LDS holds
// UNNORMALIZED w. Pass B: wave-wide uint4 gather — lane handles dims 8*(lane&31)..+7
// of edge j+(lane>>5); 2 edges per wave instruction, 4 edges in flight; cross-half
// shfl_xor(32) combine; coalesced uint4 output store.
__global__ __launch_bounds__(128) void agg_fused(const __hip_bfloat16* __restrict__ hb,
                                                 const float* __restrict__ el,
                                                 const float* __restrict__ er,
                                                 const float* __restrict__ bias,
                                                 const int* __restrict__ rowp,
                                                 const int* __restrict__ srcs,
                                                 __hip_bfloat16* __restrict__ ob) {
  __shared__ float eld[2][MAXE * 4];
  int wv = threadIdx.x >> 6, lane = threadIdx.x & 63;
  int n = blockIdx.x * 2 + wv;
  float* ew = eld[wv];
  int i0 = rowp[n], deg = rowp[n + 1] - i0;
  float4 ern4 = *reinterpret_cast<const float4*>(er + (size_t)n * 4);
  float m0 = -1e30f, m1 = -1e30f, m2 = -1e30f, m3 = -1e30f;
  float e0 = 0.f, e1 = 0.f, e2 = 0.f, e3 = 0.f;
  for (int j = lane; j < deg; j += 64) {
    int s = srcs[i0 + j];
    float4 e4 = *reinterpret_cast<const float4*>(el + (size_t)s * 4);
    e0 = e4.x + ern4.x; e0 = (e0 >= 0.f) ? e0 : 0.2f * e0;
    e1 = e4.y + ern4.y; e1 = (e1 >= 0.f) ? e1 : 0.2f * e1;
    e2 = e4.z + ern4.z; e2 = (e2 >= 0.f) ? e2 : 0.2f * e2;
    e3 = e4.w + ern4.w; e3 = (e3 >= 0.f) ? e3 : 0.2f * e3;
    if (j < MAXE)
      *reinterpret_cast<float4*>(&ew[j * 4]) = make_float4(e0, e1, e2, e3);
    m0 = fmaxf(m0, e0);
    m1 = fmaxf(m1, e1);
    m2 = fmaxf(m2, e2);
    m3 = fmaxf(m3, e3);
  }
#pragma unroll
  for (int off = 1; off < 64; off <<= 1) {
    m0 = fmaxf(m0, __shfl_xor(m0, off));
    m1 = fmaxf(m1, __shfl_xor(m1, off));
    m2 = fmaxf(m2, __shfl_xor(m2, off));
    m3 = fmaxf(m3, __shfl_xor(m3, off));
  }
  float l0 = 0.f, l1 = 0.f, l2 = 0.f, l3 = 0.f;
  if (deg <= 64) {
    if (lane < deg) {
      float w0 = __expf(e0 - m0), w1 = __expf(e1 - m1);
      float w2 = __expf(e2 - m2), w3 = __expf(e3 - m3);
      *reinterpret_cast<float4*>(&ew[lane * 4]) = make_float4(w0, w1, w2, w3);
      l0 = w0; l1 = w1; l2 = w2; l3 = w3;
    }
  } else {
    for (int j = lane; j < deg; j += 64) {
      float a0, a1, a2, a3;
      if (j < MAXE) {
        float4 q = *reinterpret_cast<const float4*>(&ew[j * 4]);
        a0 = q.x; a1 = q.y; a2 = q.z; a3 = q.w;
      } else {
        int s = srcs[i0 + j];
        float4 q = *reinterpret_cast<const float4*>(el + (size_t)s * 4);
        a0 = q.x + ern4.x; a0 = (a0 >= 0.f) ? a0 : 0.2f * a0;
        a1 = q.y + ern4.y; a1 = (a1 >= 0.f) ? a1 : 0.2f * a1;
        a2 = q.z + ern4.z; a2 = (a2 >= 0.f) ? a2 : 0.2f * a2;
        a3 = q.w + ern4.w; a3 = (a3 >= 0.f) ? a3 : 0.2f * a3;
      }
      float w0 = __expf(a0 - m0), w1 = __expf(a1 - m1);
      float w2 = __expf(a2 - m2), w3 = __expf(a3 - m3);
      if (j < MAXE)
        *reinterpret_cast<float4*>(&ew[j * 4]) = make_float4(w0, w1, w2, w3);
      l0 += w0; l1 += w1; l2 += w2; l3 += w3;
    }
  }
#pragma unroll
  for (int off = 1; off < 64; off <<= 1) {
    l0 += __shfl_xor(l0, off);
    l1 += __shfl_xor(l1, off);
    l2 += __shfl_xor(l2, off);
    l3 += __shfl_xor(l3, off);
  }
  float inv0 = (l0 > 0.f) ? (1.f / l0) : 0.f;
  float inv1 = (l1 > 0.f) ? (1.f / l1) : 0.f;
  float inv2 = (l2 > 0.f) ? (1.f / l2) : 0.f;
  float inv3 = (l3 > 0.f) ? (1.f / l3) : 0.f;
  __syncthreads();

  // ---- pass B: wave-wide uint4 gather ----
  int half = lane >> 5;
  int hl = lane & 31;              // dims 8*hl .. 8*hl+7
  int head = hl >> 3;
  float mh = (head == 0) ? m0 : (head == 1) ? m1 : (head == 2) ? m2 : m3;
  float ivh = (head == 0) ? inv0 : (head == 1) ? inv1 : (head == 2) ? inv2 : inv3;
  float ernh = (head == 0) ? ern4.x : (head == 1) ? ern4.y : (head == 2) ? ern4.z : ern4.w;
  const uint4* hp4 = (const uint4*)hb;

  f32x4 pA = {0.f, 0.f, 0.f, 0.f}, pB = {0.f, 0.f, 0.f, 0.f};
  f32x4 qA = {0.f, 0.f, 0.f, 0.f}, qB = {0.f, 0.f, 0.f, 0.f};

  auto getw = [&](int e) -> float {
    if (e < MAXE) return ew[e * 4 + head];
    int s = srcs[i0 + e];
    float q = el[s * 4 + head] + ernh;
    q = (q >= 0.f) ? q : 0.2f * q;
    return __expf(q - mh);
  };

  int j = 0;
  for (; j + 7 < deg; j += 8) {
    int s0 = srcs[i0 + j + half];
    int s1 = srcs[i0 + j + 2 + half];
    int s2 = srcs[i0 + j + 4 + half];
    int s3 = srcs[i0 + j + 6 + half];
    uint4 h0 = hp4[(size_t)s0 * 32 + hl];
    uint4 h1 = hp4[(size_t)s1 * 32 + hl];
    uint4 h2 = hp4[(size_t)s2 * 32 + hl];
    uint4 h3 = hp4[(size_t)s3 * 32 + hl];
    float w0 = getw(j + half), w1 = getw(j + 2 + half);
    float w2 = getw(j + 4 + half), w3 = getw(j + 6 + half);
    pA[0] += w0 * bflo(h0.x); pA[1] += w0 * bfhi(h0.x);
    pA[2] += w0 * bflo(h0.y); pA[3] += w0 * bfhi(h0.y);
    qA[0] += w0 * bflo(h0.z); qA[1] += w0 * bfhi(h0.z);
    qA[2] += w0 * bflo(h0.w); qA[3] += w0 * bfhi(h0.w);
    pB[0] += w1 * bflo(h1.x); pB[1] += w1 * bfhi(h1.x);
    pB[2] += w1 * bflo(h1.y); pB[3] += w1 * bfhi(h1.y);
    qB[0] += w1 * bflo(h1.z); qB[1] += w1 * bfhi(h1.z);
    qB[2] += w1 * bflo(h1.w); qB[3] += w1 * bfhi(h1.w);
    pA[0] += w2 * bflo(h2.x); pA[1] += w2 * bfhi(h2.x);
    pA[2] += w2 * bflo(h2.y); pA[3] += w2 * bfhi(h2.y);
    qA[0] += w2 * bflo(h2.z); qA[1] += w2 * bfhi(h2.z);
    qA[2] += w2 * bflo(h2.w); qA[3] += w2 * bfhi(h2.w);
    pB[0] += w3 * bflo(h3.x); pB[1] += w3 * bfhi(h3.x);
    pB[2] += w3 * bflo(h3.y); pB[3] += w3 * bfhi(h3.y);
    qB[0] += w3 * bflo(h3.z); qB[1] += w3 * bfhi(h3.z);
    qB[2] += w3 * bflo(h3.w); qB[3] += w3 * bfhi(h3.w);
  }
  for (; j + 1 < deg; j += 2) {
    int s = srcs[i0 + j + half];
    uint4 h = hp4[(size_t)s * 32 + hl];
    float w = getw(j + half);
    pA[0] += w * bflo(h.x); pA[1] += w * bfhi(h.x);
    pA[2] += w * bflo(h.y); pA[3] += w * bfhi(h.y);
    qA[0] += w * bflo(h.z); qA[1] += w * bfhi(h.z);
    qA[2] += w * bflo(h.w); qA[3] += w * bfhi(h.w);
  }
  if (j < deg && half == 0) {  // odd tail: lanes 0-31 only
    int s = srcs[i0 + j];
    uint4 h = hp4[(size_t)s * 32 + hl];
    float w = getw(j);
    pA[0] += w * bflo(h.x); pA[1] += w * bfhi(h.x);
    pA[2] += w * bflo(h.y); pA[3] += w * bfhi(h.y);
    qA[0] += w * bflo(h.z); qA[1] += w * bfhi(h.z);
    qA[2] += w * bflo(h.w); qA[3] += w * bfhi(h.w);
  }
  pA += pB;
  qA += qB;
#pragma unroll
  for (int d = 0; d < 4; ++d) {
    pA[d] += __shfl_xor(pA[d], 32);
    qA[d] += __shfl_xor(qA[d], 32);
  }
  if (half == 0) {
    float4 bA = *reinterpret_cast<const float4*>(bias + (size_t)hl * 8);
    float4 bBv = *reinterpret_cast<const float4*>(bias + (size_t)hl * 8 + 4);
    float r0 = pA[0] * ivh + bA.x;
    float r1 = pA[1] * ivh + bA.y;
    float r2 = pA[2] * ivh + bA.z;
    float r3 = pA[3] * ivh + bA.w;
    float r4 = qA[0] * ivh + bBv.x;
    float r5 = qA[1] * ivh + bBv.y;
    float r6 = qA[2] * ivh + bBv.z;
    float r7 = qA[3] * ivh + bBv.w;
    r0 = (r0 > 0.f) ? r0 : (__expf(r0) - 1.f);
    r1 = (r1 > 0.f) ? r1 : (__expf(r1) - 1.f);
    r2 = (r2 > 0.f) ? r2 : (__expf(r2) - 1.f);
    r3 = (r3 > 0.f) ? r3 : (__expf(r3) - 1.f);
    r4 = (r4 > 0.f) ? r4 : (__expf(r4) - 1.f);
    r5 = (r5 > 0.f) ? r5 : (__expf(r5) - 1.f);
    r6 = (r6 > 0.f) ? r6 : (__expf(r6) - 1.f);
    r7 = (r7 > 0.f) ? r7 : (__expf(r7) - 1.f);
    __hip_bfloat16 c0 = __float2bfloat16(r0), c1 = __float2bfloat16(r1);
    __hip_bfloat16 c2 = __float2bfloat16(r2), c3 = __float2bfloat16(r3);
    __hip_bfloat16 c4 = __float2bfloat16(r4), c5 = __float2bfloat16(r5);
    __hip_bfloat16 c6 = __float2bfloat16(r6), c7 = __float2bfloat16(r7);
    uint4 o;
    o.x = (unsigned int)(*(unsigned short*)&c0) | ((unsigned int)(*(unsigned short*)&c1) << 16);
    o.y = (unsigned int)(*(unsigned short*)&c2) | ((unsigned int)(*(unsigned short*)&c3) << 16);
    o.z = (unsigned int)(*(unsigned short*)&c4) | ((unsigned int)(*(unsigned short*)&c5) << 16);
    o.w = (unsigned int)(*(unsigned short*)&c6) | ((unsigned int)(*(unsigned short*)&c7) << 16);
    ((uint4*)ob)[(size_t)n * 32 + hl] = o;
  }
}

// ---------------- layer 3: fused stats + gather + bias + log_softmax (2 nodes/block) --
__global__ __launch_bounds__(128) void agg_cls_fused(const __hip_bfloat16* __restrict__ h3b,
                                                     const float* __restrict__ el3,
                                                     const float* __restrict__ er3,
                                                     const float* __restrict__ bias,
                                                     const int* __restrict__ rowp,
                                                     const int* __restrict__ srcs,
                                                     float* __restrict__ out) {
  __shared__ float eldc[2][MAXE];
  int wv = threadIdx.x >> 6, lane = threadIdx.x & 63;
  int n = blockIdx.x * 2 + wv;
  float* ec = eldc[wv];
  int i0 = rowp[n], deg = rowp[n + 1] - i0;
  float ern = er3[n];
  float m = -1e30f, e = 0.f;
  for (int j = lane; j < deg; j += 64) {
    int s = srcs[i0 + j];
    e = el3[s] + ern;
    e = (e >= 0.f) ? e : 0.2f * e;
    if (j < MAXE) ec[j] = e;
    m = fmaxf(m, e);
  }
#pragma unroll
  for (int off = 1; off < 64; off <<= 1) m = fmaxf(m, __shfl_xor(m, off));
  float l = 0.f;
  if (deg <= 64) {
    if (lane < deg) {
      float w = __expf(e - m);
      ec[lane] = w;
      l = w;
    }
  } else {
    for (int j = lane; j < deg; j += 64) {
      float a;
      if (j < MAXE) {
        a = ec[j];
      } else {
        int s = srcs[i0 + j];
        a = el3[s] + ern;
        a = (a >= 0.f) ? a : 0.2f * a;
      }
      float w = __expf(a - m);
      if (j < MAXE) ec[j] = w;
      l += w;
    }
  }
#pragma unroll
  for (int off = 1; off < 64; off <<= 1) l += __shfl_xor(l, off);
  float inv = (l > 0.f) ? (1.f / l) : 0.f;
  __syncthreads();
  bool act2 = lane < ((NCLASS + 1) / 2);  // lane < 20, dims {2*lane, 2*lane+1}
  const unsigned int* hp3 = (const unsigned int*)h3b;
  float ax = 0.f, ay = 0.f, bx = 0.f, by = 0.f;
  int j = 0;
  for (; j + 1 < deg; j += 2) {
    int s0 = srcs[i0 + j], s1 = srcs[i0 + j + 1];
    float w0, w1;
    if (j + 1 < MAXE) {
      w0 = ec[j];
      w1 = ec[j + 1];
    } else {
      float q0 = el3[s0] + ern; q0 = (q0 >= 0.f) ? q0 : 0.2f * q0;
      float q1 = el3[s1] + ern; q1 = (q1 >= 0.f) ? q1 : 0.2f * q1;
      w0 = __expf(q0 - m);
      w1 = __expf(q1 - m);
    }
    if (act2) {
      unsigned int h0 = hp3[(size_t)s0 * 32 + lane];
      unsigned int h1 = hp3[(size_t)s1 * 32 + lane];
      ax += w0 * bflo(h0);
      ay += w0 * bfhi(h0);
      bx += w1 * bflo(h1);
      by += w1 * bfhi(h1);
    }
  }
  if (j < deg) {
    int s0 = srcs[i0 + j];
    float w0;
    if (j < MAXE) {
      w0 = ec[j];
    } else {
      float q0 = el3[s0] + ern; q0 = (q0 >= 0.f) ? q0 : 0.2f * q0;
      w0 = __expf(q0 - m);
    }
    if (act2) {
      unsigned int h0 = hp3[(size_t)s0 * 32 + lane];
      ax += w0 * bflo(h0);
      ay += w0 * bfhi(h0);
    }
  }
  float z0 = (ax + bx) * inv + (act2 ? bias[2 * lane] : 0.f);
  float z1 = (ay + by) * inv + (act2 ? bias[2 * lane + 1] : 0.f);
  float mx = act2 ? fmaxf(z0, z1) : -1e30f;
  for (int off = 32; off > 0; off >>= 1) mx = fmaxf(mx, __shfl_xor(mx, off));
  float sm = act2 ? (__expf(z0 - mx) + __expf(z1 - mx)) : 0.f;
  for (int off = 32; off > 0; off >>= 1) sm += __shfl_xor(sm, off);
  float ls = __logf(sm);
  if (act2) {
    float2 r;
    r.x = z0 - mx - ls;
    r.y = z1 - mx - ls;
    *reinterpret_cast<float2*>(out + (size_t)n * NCLASS + 2 * lane) = r;
  }
}

extern "C" void kernel_launch(void* const* d_in, const int* in_sizes, int n_in,
                              void* d_out, int out_size, void* d_ws, size_t ws_size,
                              hipStream_t stream) {
  const float* x   = (const float*)d_in[0];
  const int* edges = (const int*)d_in[1];
  const float* W1  = (const float*)d_in[2];
  const float* al1 = (const float*)d_in[3];
  const float* ar1 = (const float*)d_in[4];
  const float* b1  = (const float*)d_in[5];
  const float* W2  = (const float*)d_in[6];
  const float* al2 = (const float*)d_in[7];
  const float* ar2 = (const float*)d_in[8];
  const float* b2  = (const float*)d_in[9];
  const float* W3  = (const float*)d_in[10];
  const float* al3 = (const float*)d_in[11];
  const float* ar3 = (const float*)d_in[12];
  const float* b3  = (const float*)d_in[13];
  float* out = (float*)d_out;

  const size_t N = N_NODES, E = N_EDGES;
  float* el  = (float*)d_ws;             // [N,4]
  float* er  = el + N * 4;               // [N,4]
  float* el3 = er + N * 4;               // [N]
  float* er3 = el3 + N;                  // [N]
  __hip_bfloat16* xb = (__hip_bfloat16*)(er3 + N);  // [N,256]
  __hip_bfloat16* hb = xb + N * 256;     // [N,256]
  __hip_bfloat16* ob = hb + N * 256;     // [N,256]
  __hip_bfloat16* h3b = ob + N * 256;    // [N,64]
  __hip_bfloat16* WT1 = h3b + N * 64;    // [256,256]
  __hip_bfloat16* WT2 = WT1 + 256 * 256; // [256,256]
  __hip_bfloat16* WT3 = WT2 + 256 * 256; // [64,256]
  int* rowp   = (int*)(WT3 + 64 * 256);  // [N+1]
  int* cursor = rowp + (N + 1);          // [N]
  int* srcs   = cursor + N;              // [E]
  int* deg    = srcs + E;                // [N]
  int* bsums  = deg + N;                 // [256]
  int* s32    = bsums + 256;             // [E]
  int* d32    = s32 + E;                 // [E]
  int* flag   = d32 + E;                 // [1]

  hipMemsetAsync(deg, 0, N * sizeof(int), stream);
  detect_i64<<<1, 64, 0, stream>>>(edges, flag);
  int eb = (int)((E + 255) / 256);
  norm_count<<<eb, 256, 0, stream>>>(edges, flag, s32, d32, deg);
  int nb = (int)((N + 255) / 256);
  scan_bsum<<<nb, 256, 0, stream>>>(deg, bsums);
  scan_offsets<<<1, 256, 0, stream>>>(bsums, rowp, nb);
  scan_final<<<nb, 256, 0, stream>>>(deg, bsums, rowp, cursor);
  scatter_edges<<<eb, 256, 0, stream>>>(s32, d32, cursor, srcs);

  cast_x<<<(unsigned)(N * 256 / 4 / 256), 256, 0, stream>>>(x, xb);
  prep_w<<<576, 256, 0, stream>>>(W1, W2, W3, WT1, WT2, WT3);

  dim3 gg((unsigned)((N + 127) / 128), 2);  // 391 x 2
  dim3 g3((unsigned)((N + 127) / 128), 1);

  // layer 1
  gemm_gat12<<<gg, 256, 0, stream>>>(xb, WT1, al1, ar1, hb, el, er);
  agg_fused<<<(unsigned)(N / 2), 128, 0, stream>>>(hb, el, er, b1, rowp, srcs, ob);
  // layer 2
  gemm_gat12<<<gg, 256, 0, stream>>>(ob, WT2, al2, ar2, hb, el, er);
  agg_fused<<<(unsigned)(N / 2), 128, 0, stream>>>(hb, el, er, b2, rowp, srcs, ob);
  // layer 3 + fused log_softmax
  gemm_gat3<<<g3, 256, 0, stream>>>(ob, WT3, al3, ar3, h3b, el3, er3);
  agg_cls_fused<<<(unsigned)(N / 2), 128, 0, stream>>>(h3b, el3, er3, b3, rowp, srcs, out);
}